// Round 2
// baseline (885.611 us; speedup 1.0000x reference)
//
#include <hip/hip_runtime.h>
#include <hip/hip_bf16.h>

#define NN 100000
#define EE 1600000
#define RR 8
#define DD 64
#define MM (NN * RR)                 // 800000 segments
#define SCAN_CHUNK 1024
#define NBLK2 ((MM + SCAN_CHUNK - 1) / SCAN_CHUNK)   // 782
#define BN_EPS 1e-5f

static __device__ __forceinline__ unsigned short f32_to_bf16(float f) {
    unsigned int u = __float_as_uint(f);
    unsigned int r = u + 0x7FFFu + ((u >> 16) & 1u);   // RNE
    return (unsigned short)(r >> 16);
}

// ---------------- CSR build, keyed by (dst*8 + rel) ----------------

__global__ void k_count(const int* __restrict__ dst, const int* __restrict__ et,
                        int* __restrict__ deg) {
    int e = blockIdx.x * 256 + threadIdx.x;
    if (e < EE) atomicAdd(&deg[dst[e] * RR + et[e]], 1);
}

__global__ void k_scan1(const int* __restrict__ deg, int* __restrict__ part) {
    __shared__ int sdata[256];
    int t = threadIdx.x;
    int base = blockIdx.x * SCAN_CHUNK;
    int s = 0;
#pragma unroll
    for (int j = 0; j < 4; ++j) {
        int i = base + t * 4 + j;
        s += (i < MM) ? deg[i] : 0;
    }
    sdata[t] = s;
    __syncthreads();
    for (int off = 128; off > 0; off >>= 1) {
        if (t < off) sdata[t] += sdata[t + off];
        __syncthreads();
    }
    if (t == 0) part[blockIdx.x] = sdata[0];
}

// parallel scan over the 782 block partials (single 1024-thread block)
__global__ void k_scan2(const int* __restrict__ part, int* __restrict__ pscan,
                        int* __restrict__ rowptr) {
    __shared__ int sdata[1024];
    int t = threadIdx.x;
    int v = (t < NBLK2) ? part[t] : 0;
    sdata[t] = v;
    __syncthreads();
    for (int off = 1; off < 1024; off <<= 1) {
        int x = (t >= off) ? sdata[t - off] : 0;
        __syncthreads();
        sdata[t] += x;
        __syncthreads();
    }
    if (t < NBLK2) pscan[t] = sdata[t] - v;     // exclusive prefix
    if (t == NBLK2 - 1) rowptr[MM] = sdata[t];  // total == EE
}

__global__ void k_scan3(const int* __restrict__ deg, const int* __restrict__ pscan,
                        int* __restrict__ rowptr, int* __restrict__ cursor) {
    __shared__ int sdata[256];
    int t = threadIdx.x;
    int base = blockIdx.x * SCAN_CHUNK;
    int v[4];
    int s = 0;
#pragma unroll
    for (int j = 0; j < 4; ++j) {
        int i = base + t * 4 + j;
        v[j] = (i < MM) ? deg[i] : 0;
        s += v[j];
    }
    sdata[t] = s;
    __syncthreads();
    for (int off = 1; off < 256; off <<= 1) {
        int x = (t >= off) ? sdata[t - off] : 0;
        __syncthreads();
        sdata[t] += x;
        __syncthreads();
    }
    int run = pscan[blockIdx.x] + sdata[t] - s;   // exclusive prefix for this thread
#pragma unroll
    for (int j = 0; j < 4; ++j) {
        int i = base + t * 4 + j;
        if (i < MM) { rowptr[i] = run; cursor[i] = run; }
        run += v[j];
    }
}

__global__ void k_fill(const int* __restrict__ src, const int* __restrict__ dst,
                       const int* __restrict__ et, int* __restrict__ cursor,
                       int* __restrict__ rec) {
    int e = blockIdx.x * 256 + threadIdx.x;
    if (e < EE) {
        int key = dst[e] * RR + et[e];
        int pos = atomicAdd(&cursor[key], 1);
        rec[pos] = src[e];
    }
}

// ---------------- aggregation: one wave per dst, plain sums per segment ----------------
// mean layout: [N][64][8]  (k = d*8 + r) -> one 16B store per lane

__global__ void k_agg(const float* __restrict__ X, const int* __restrict__ rowptr,
                      const int* __restrict__ rec, unsigned short* __restrict__ mean) {
    int wave = threadIdx.x >> 6;
    int lane = threadIdx.x & 63;
    int n = blockIdx.x * 4 + wave;
    if (n >= NN) return;
    union { unsigned short u[8]; uint4 v; } pk;
    int e0 = rowptr[n * RR];
#pragma unroll 1
    for (int r = 0; r < RR; ++r) {
        int e1 = rowptr[n * RR + r + 1];
        int cnt = e1 - e0;
        float acc = 0.f;
        for (int eb = e0; eb < e1; eb += 64) {
            int rv = (eb + lane < e1) ? rec[eb + lane] : 0;
            int m = e1 - eb; if (m > 64) m = 64;
            for (int i = 0; i < m; ++i) {
                int s = __shfl(rv, i);
                acc += X[(size_t)s * DD + lane];
            }
        }
        float c = (float)(cnt > 1 ? cnt : 1);
        pk.u[r] = f32_to_bf16(acc / c);
        e0 = e1;
    }
    *(uint4*)(mean + (size_t)n * (RR * DD) + lane * RR) = pk.v;
}

// ---------------- weight prep: Wc[576][64] = permuted W (k=d*8+r) ‖ root ----------------

__global__ void k_prepw(const float* __restrict__ W, const float* __restrict__ Root,
                        float* __restrict__ Wc) {
    int i = blockIdx.x * 256 + threadIdx.x;   // over 576*64
    if (i >= 576 * 64) return;
    int o = i & 63;
    int k = i >> 6;
    float v;
    if (k < 512) {
        int d = k >> 3;
        int r = k & 7;
        v = W[(size_t)r * 4096 + d * 64 + o];
    } else {
        v = Root[(k - 512) * 64 + o];
    }
    Wc[i] = v;
}

// ---------------- fused GEMM: out = [mean | X] @ Wc + bias ----------------
// mean: [N][512] bf16 ; X: [N][64] f32 ; Wc: [576][64] f32

#define LDSTRIDE 68

__global__ __launch_bounds__(256) void k_gemm(const unsigned short* __restrict__ meanB,
                                              const float* __restrict__ Xf,
                                              const float* __restrict__ Wc,
                                              const float* __restrict__ bias,
                                              float* __restrict__ Out) {
    __shared__ float a_s[64 * LDSTRIDE];
    __shared__ float w_s[64 * LDSTRIDE];
    int t = threadIdx.x;
    int n0 = blockIdx.x * 64;
    int tx = t & 15;
    int ty = t >> 4;
    int row_ld = t >> 2;    // 0..63
    int kseg = (t & 3) * 16;

    float acc[4][4] = {};

    for (int c = 0; c < 9; ++c) {
        // stage Wc rows c*64 .. c*64+63
#pragma unroll
        for (int j = 0; j < 4; ++j) {
            float4 wv = *(const float4*)(Wc + (size_t)(c * 64 + row_ld) * 64 + kseg + j * 4);
            *(float4*)&w_s[row_ld * LDSTRIDE + kseg + j * 4] = wv;
        }
        int n = n0 + row_ld;
        if (c < 8) {
            unsigned short u[16];
            if (n < NN) {
                const uint4* p = (const uint4*)(meanB + (size_t)n * 512 + c * 64 + kseg);
                uint4 v0 = p[0];
                uint4 v1 = p[1];
                *(uint4*)&u[0] = v0;
                *(uint4*)&u[8] = v1;
            } else {
#pragma unroll
                for (int j = 0; j < 16; ++j) u[j] = 0;
            }
#pragma unroll
            for (int j = 0; j < 16; ++j) {
                a_s[(kseg + j) * LDSTRIDE + row_ld] =
                    __uint_as_float(((unsigned int)u[j]) << 16);
            }
        } else {
#pragma unroll
            for (int j = 0; j < 4; ++j) {
                float4 v;
                if (n < NN) v = *(const float4*)(Xf + (size_t)n * 64 + kseg + j * 4);
                else v = make_float4(0.f, 0.f, 0.f, 0.f);
                a_s[(kseg + j * 4 + 0) * LDSTRIDE + row_ld] = v.x;
                a_s[(kseg + j * 4 + 1) * LDSTRIDE + row_ld] = v.y;
                a_s[(kseg + j * 4 + 2) * LDSTRIDE + row_ld] = v.z;
                a_s[(kseg + j * 4 + 3) * LDSTRIDE + row_ld] = v.w;
            }
        }
        __syncthreads();
#pragma unroll 16
        for (int kk = 0; kk < 64; ++kk) {
            float4 av = *(const float4*)&a_s[kk * LDSTRIDE + 4 * ty];
            float4 bv = *(const float4*)&w_s[kk * LDSTRIDE + 4 * tx];
            acc[0][0] += av.x * bv.x; acc[0][1] += av.x * bv.y;
            acc[0][2] += av.x * bv.z; acc[0][3] += av.x * bv.w;
            acc[1][0] += av.y * bv.x; acc[1][1] += av.y * bv.y;
            acc[1][2] += av.y * bv.z; acc[1][3] += av.y * bv.w;
            acc[2][0] += av.z * bv.x; acc[2][1] += av.z * bv.y;
            acc[2][2] += av.z * bv.z; acc[2][3] += av.z * bv.w;
            acc[3][0] += av.w * bv.x; acc[3][1] += av.w * bv.y;
            acc[3][2] += av.w * bv.z; acc[3][3] += av.w * bv.w;
        }
        __syncthreads();
    }

    float4 bb = *(const float4*)(bias + 4 * tx);
#pragma unroll
    for (int i = 0; i < 4; ++i) {
        int n = n0 + 4 * ty + i;
        if (n < NN) {
            float4 o;
            o.x = acc[i][0] + bb.x;
            o.y = acc[i][1] + bb.y;
            o.z = acc[i][2] + bb.z;
            o.w = acc[i][3] + bb.w;
            *(float4*)(Out + (size_t)n * 64 + 4 * tx) = o;
        }
    }
}

// ---------------- BN column stats + BN+ReLU (in-place) ----------------

__global__ void k_colstats(const float* __restrict__ H, float* __restrict__ stats) {
    int t = threadIdx.x;
    int col = t & 63;
    int rl = t >> 6;   // 0..3
    float s = 0.f, sq = 0.f;
    for (int n = blockIdx.x * 4 + rl; n < NN; n += gridDim.x * 4) {
        float v = H[(size_t)n * 64 + col];
        s += v;
        sq += v * v;
    }
    __shared__ float ss[256], sv[256];
    ss[t] = s; sv[t] = sq;
    __syncthreads();
    if (t < 128) { ss[t] += ss[t + 128]; sv[t] += sv[t + 128]; }
    __syncthreads();
    if (t < 64) {
        atomicAdd(&stats[col], ss[t] + ss[t + 64]);
        atomicAdd(&stats[64 + col], sv[t] + sv[t + 64]);
    }
}

__global__ void k_bnrelu(float* __restrict__ H, const float* __restrict__ stats,
                         const float* __restrict__ gamma, const float* __restrict__ beta) {
    int idx = blockIdx.x * 256 + threadIdx.x;   // float4 index
    const int total = NN * DD / 4;
    if (idx >= total) return;
    int c0 = (idx & 15) * 4;
    float4 v = ((const float4*)H)[idx];
    float inv = 1.0f / (float)NN;
    float4 o;
    {
        float mu = stats[c0 + 0] * inv;
        float var = stats[64 + c0 + 0] * inv - mu * mu;
        float sc = gamma[c0 + 0] * rsqrtf(var + BN_EPS);
        float r = sc * (v.x - mu) + beta[c0 + 0];
        o.x = r > 0.f ? r : 0.f;
    }
    {
        float mu = stats[c0 + 1] * inv;
        float var = stats[64 + c0 + 1] * inv - mu * mu;
        float sc = gamma[c0 + 1] * rsqrtf(var + BN_EPS);
        float r = sc * (v.y - mu) + beta[c0 + 1];
        o.y = r > 0.f ? r : 0.f;
    }
    {
        float mu = stats[c0 + 2] * inv;
        float var = stats[64 + c0 + 2] * inv - mu * mu;
        float sc = gamma[c0 + 2] * rsqrtf(var + BN_EPS);
        float r = sc * (v.z - mu) + beta[c0 + 2];
        o.z = r > 0.f ? r : 0.f;
    }
    {
        float mu = stats[c0 + 3] * inv;
        float var = stats[64 + c0 + 3] * inv - mu * mu;
        float sc = gamma[c0 + 3] * rsqrtf(var + BN_EPS);
        float r = sc * (v.w - mu) + beta[c0 + 3];
        o.w = r > 0.f ? r : 0.f;
    }
    ((float4*)H)[idx] = o;
}

// ---------------- launch ----------------

static inline size_t alignup(size_t x) { return (x + 255) & ~(size_t)255; }

extern "C" void kernel_launch(void* const* d_in, const int* in_sizes, int n_in,
                              void* d_out, int out_size, void* d_ws, size_t ws_size,
                              hipStream_t stream) {
    const float* x      = (const float*)d_in[0];
    const int*   eidx   = (const int*)d_in[1];     // [2][E]: src then dst
    const int*   etype  = (const int*)d_in[2];
    const float* w1     = (const float*)d_in[3];
    const float* root1  = (const float*)d_in[4];
    const float* b1     = (const float*)d_in[5];
    const float* gamma1 = (const float*)d_in[6];
    const float* beta1  = (const float*)d_in[7];
    const float* w2     = (const float*)d_in[8];
    const float* root2  = (const float*)d_in[9];
    const float* b2     = (const float*)d_in[10];
    float* out = (float*)d_out;

    const int* src = eidx;
    const int* dst = eidx + EE;

    char* w = (char*)d_ws;
    int* deg    = (int*)w;            w += alignup((size_t)MM * 4);
    int* rowptr = (int*)w;            w += alignup((size_t)(MM + 1) * 4);
    int* cursor = (int*)w;            w += alignup((size_t)MM * 4);
    int* part   = (int*)w;            w += alignup(1024 * 4);
    int* pscan  = (int*)w;            w += alignup(1024 * 4);
    int* rec    = (int*)w;            w += alignup((size_t)EE * 4);
    unsigned short* mean = (unsigned short*)w; w += alignup((size_t)NN * RR * DD * 2);
    float* h    = (float*)w;          w += alignup((size_t)NN * DD * 4);
    float* wc1  = (float*)w;          w += alignup((size_t)576 * 64 * 4);
    float* wc2  = (float*)w;          w += alignup((size_t)576 * 64 * 4);
    float* stats = (float*)w;         w += alignup(128 * 4);

    hipMemsetAsync(deg, 0, (size_t)MM * 4, stream);
    hipMemsetAsync(stats, 0, 128 * 4, stream);

    // weight prep (permuted concat)
    k_prepw<<<dim3(144), dim3(256), 0, stream>>>(w1, root1, wc1);
    k_prepw<<<dim3(144), dim3(256), 0, stream>>>(w2, root2, wc2);

    // CSR build keyed by (dst*8+rel), shared by both layers
    k_count<<<dim3(EE / 256), dim3(256), 0, stream>>>(dst, etype, deg);
    k_scan1<<<dim3(NBLK2), dim3(256), 0, stream>>>(deg, part);
    k_scan2<<<dim3(1), dim3(1024), 0, stream>>>(part, pscan, rowptr);
    k_scan3<<<dim3(NBLK2), dim3(256), 0, stream>>>(deg, pscan, rowptr, cursor);
    k_fill<<<dim3(EE / 256), dim3(256), 0, stream>>>(src, dst, etype, cursor, rec);

    // layer 1
    k_agg<<<dim3((NN + 3) / 4), dim3(256), 0, stream>>>(x, rowptr, rec, mean);
    k_gemm<<<dim3((NN + 63) / 64), dim3(256), 0, stream>>>(mean, x, wc1, b1, h);
    k_colstats<<<dim3(256), dim3(256), 0, stream>>>(h, stats);
    k_bnrelu<<<dim3(NN * DD / 4 / 256), dim3(256), 0, stream>>>(h, stats, gamma1, beta1);

    // layer 2
    k_agg<<<dim3((NN + 3) / 4), dim3(256), 0, stream>>>(h, rowptr, rec, mean);
    k_gemm<<<dim3((NN + 63) / 64), dim3(256), 0, stream>>>(mean, h, wc2, b2, out);
}

// Round 3
// 608.961 us; speedup vs baseline: 1.4543x; 1.4543x over previous
//
#include <hip/hip_runtime.h>
#include <hip/hip_bf16.h>

#define NN 100000
#define EE 1600000
#define RR 8
#define DD 64
#define MM (NN * RR)                 // 800000 segments
#define SCAN_CHUNK 1024
#define NBLK2 ((MM + SCAN_CHUNK - 1) / SCAN_CHUNK)   // 782
#define BN_EPS 1e-5f
#define KTOT 576                     // 512 (rel) + 64 (root)

typedef __bf16 bf16x8 __attribute__((ext_vector_type(8)));
typedef float  f32x4  __attribute__((ext_vector_type(4)));

static __device__ __forceinline__ unsigned short f32_to_bf16(float f) {
    unsigned int u = __float_as_uint(f);
    unsigned int r = u + 0x7FFFu + ((u >> 16) & 1u);   // RNE
    return (unsigned short)(r >> 16);
}
static __device__ __forceinline__ float bflo(unsigned int u) {
    return __uint_as_float(u << 16);
}
static __device__ __forceinline__ float bfhi(unsigned int u) {
    return __uint_as_float(u & 0xFFFF0000u);
}

// ---------------- CSR build, keyed by (dst*8 + rel) ----------------

__global__ void k_count(const int* __restrict__ dst, const int* __restrict__ et,
                        int* __restrict__ deg) {
    int e = blockIdx.x * 256 + threadIdx.x;
    if (e < EE) atomicAdd(&deg[dst[e] * RR + et[e]], 1);
}

__global__ void k_scan1(const int* __restrict__ deg, int* __restrict__ part) {
    __shared__ int sdata[256];
    int t = threadIdx.x;
    int base = blockIdx.x * SCAN_CHUNK;
    int s = 0;
#pragma unroll
    for (int j = 0; j < 4; ++j) {
        int i = base + t * 4 + j;
        s += (i < MM) ? deg[i] : 0;
    }
    sdata[t] = s;
    __syncthreads();
    for (int off = 128; off > 0; off >>= 1) {
        if (t < off) sdata[t] += sdata[t + off];
        __syncthreads();
    }
    if (t == 0) part[blockIdx.x] = sdata[0];
}

__global__ void k_scan2(const int* __restrict__ part, int* __restrict__ pscan,
                        int* __restrict__ rowptr) {
    __shared__ int sdata[1024];
    int t = threadIdx.x;
    int v = (t < NBLK2) ? part[t] : 0;
    sdata[t] = v;
    __syncthreads();
    for (int off = 1; off < 1024; off <<= 1) {
        int x = (t >= off) ? sdata[t - off] : 0;
        __syncthreads();
        sdata[t] += x;
        __syncthreads();
    }
    if (t < NBLK2) pscan[t] = sdata[t] - v;
    if (t == NBLK2 - 1) rowptr[MM] = sdata[t];
}

// cursor may alias deg: reads of deg[i] precede writes of cursor[i] in-thread
__global__ void k_scan3(const int* __restrict__ deg, const int* __restrict__ pscan,
                        int* __restrict__ rowptr, int* __restrict__ cursor) {
    __shared__ int sdata[256];
    int t = threadIdx.x;
    int base = blockIdx.x * SCAN_CHUNK;
    int v[4];
    int s = 0;
#pragma unroll
    for (int j = 0; j < 4; ++j) {
        int i = base + t * 4 + j;
        v[j] = (i < MM) ? deg[i] : 0;
        s += v[j];
    }
    sdata[t] = s;
    __syncthreads();
    for (int off = 1; off < 256; off <<= 1) {
        int x = (t >= off) ? sdata[t - off] : 0;
        __syncthreads();
        sdata[t] += x;
        __syncthreads();
    }
    int run = pscan[blockIdx.x] + sdata[t] - s;
#pragma unroll
    for (int j = 0; j < 4; ++j) {
        int i = base + t * 4 + j;
        if (i < MM) { rowptr[i] = run; cursor[i] = run; }
        run += v[j];
    }
}

__global__ void k_fill(const int* __restrict__ src, const int* __restrict__ dst,
                       const int* __restrict__ et, int* __restrict__ cursor,
                       int* __restrict__ rec) {
    int e = blockIdx.x * 256 + threadIdx.x;
    if (e < EE) {
        int key = dst[e] * RR + et[e];
        int pos = atomicAdd(&cursor[key], 1);
        rec[pos] = src[e];
    }
}

// ---------------- fp32 -> bf16 row conversion ----------------

__global__ void k_tobf16(const float* __restrict__ X, unsigned short* __restrict__ Xb) {
    int i = blockIdx.x * 256 + threadIdx.x;   // float4 groups
    if (i >= NN * DD / 4) return;
    float4 v = ((const float4*)X)[i];
    ushort4 o;
    o.x = f32_to_bf16(v.x); o.y = f32_to_bf16(v.y);
    o.z = f32_to_bf16(v.z); o.w = f32_to_bf16(v.w);
    ((ushort4*)Xb)[i] = o;
}

// ---------------- aggregation: wave per dst, 8 lanes per segment ----------------
// mean layout: [N][512] bf16, k = r*64 + d. Lane (r=lane>>3, q=lane&7) owns
// dims q*8..q*8+7 of segment r. One iteration = 8 edges' rows in flight.

__global__ void k_agg(const unsigned short* __restrict__ Xb,
                      const int* __restrict__ rowptr,
                      const int* __restrict__ rec,
                      unsigned short* __restrict__ mean) {
    int wv = threadIdx.x >> 6;
    int lane = threadIdx.x & 63;
    int n = blockIdx.x * 4 + wv;
    if (n >= NN) return;
    int r = lane >> 3;       // segment 0..7
    int q = lane & 7;        // dim-octet 0..7
    int e0 = rowptr[n * RR + r];
    int e1 = rowptr[n * RR + r + 1];
    float acc[8] = {0.f, 0.f, 0.f, 0.f, 0.f, 0.f, 0.f, 0.f};
    for (int e = e0; e < e1; ++e) {
        int s = rec[e];                       // uniform within 8-lane group
        uint4 u = *(const uint4*)(Xb + (size_t)s * DD + q * 8);
        acc[0] += bflo(u.x); acc[1] += bfhi(u.x);
        acc[2] += bflo(u.y); acc[3] += bfhi(u.y);
        acc[4] += bflo(u.z); acc[5] += bfhi(u.z);
        acc[6] += bflo(u.w); acc[7] += bfhi(u.w);
    }
    int cnt = e1 - e0;
    float inv = 1.0f / (float)(cnt > 1 ? cnt : 1);
    uint4 o;
    o.x = (unsigned)f32_to_bf16(acc[0] * inv) | ((unsigned)f32_to_bf16(acc[1] * inv) << 16);
    o.y = (unsigned)f32_to_bf16(acc[2] * inv) | ((unsigned)f32_to_bf16(acc[3] * inv) << 16);
    o.z = (unsigned)f32_to_bf16(acc[4] * inv) | ((unsigned)f32_to_bf16(acc[5] * inv) << 16);
    o.w = (unsigned)f32_to_bf16(acc[6] * inv) | ((unsigned)f32_to_bf16(acc[7] * inv) << 16);
    *(uint4*)(mean + (size_t)n * 512 + r * 64 + q * 8) = o;
}

// ---------------- weight prep: WcT[64][576] bf16, k = r*64+d (+root tail) ----------------

__global__ void k_prepw(const float* __restrict__ W, const float* __restrict__ Root,
                        unsigned short* __restrict__ WcT) {
    int i = blockIdx.x * 256 + threadIdx.x;   // over 64*576
    if (i >= 64 * KTOT) return;
    int o = i / KTOT;
    int k = i - o * KTOT;
    float v;
    if (k < 512) v = W[(size_t)(k >> 6) * 4096 + (k & 63) * 64 + o];
    else         v = Root[(k - 512) * 64 + o];
    WcT[(size_t)o * KTOT + k] = f32_to_bf16(v);
}

// ---------------- MFMA GEMM: out[N][64] = [mean | Xb] @ Wc + bias ----------------
// wave handles 16 rows x 64 cols; 4 waves/block -> 64 rows/block.
// A frag: lane holds A[m=lane&15][k0 + quad*8 + j] (16B contiguous load).
// B frag: lane holds Wc[k0+quad*8+j][n=lane&15] = WcT[n][k0+quad*8+j].
// D: row = quad*4 + i, col = lane&15.

__global__ __launch_bounds__(256) void k_gemm(const unsigned short* __restrict__ meanB,
                                              const unsigned short* __restrict__ Xb,
                                              const unsigned short* __restrict__ WcT,
                                              const float* __restrict__ bias,
                                              float* __restrict__ Out) {
    int t = threadIdx.x;
    int wv = t >> 6, lane = t & 63;
    int quad = lane >> 4, m16 = lane & 15;
    int row0 = blockIdx.x * 64 + wv * 16;
    int arow = row0 + m16;
    bool rowok = arow < NN;

    union AU { uint4 u; bf16x8 f; };
    f32x4 acc[4] = {{0.f,0.f,0.f,0.f},{0.f,0.f,0.f,0.f},{0.f,0.f,0.f,0.f},{0.f,0.f,0.f,0.f}};

    const unsigned short* aptr = meanB + (size_t)arow * 512 + quad * 8;
    const unsigned short* xptr = Xb + (size_t)arow * DD + quad * 8;
    const unsigned short* wptr = WcT + (size_t)m16 * KTOT + quad * 8;

#pragma unroll
    for (int kb = 0; kb < 16; ++kb) {
        AU a;
        if (rowok) a.u = *(const uint4*)(aptr + kb * 32);
        else a.u = make_uint4(0, 0, 0, 0);
#pragma unroll
        for (int nt = 0; nt < 4; ++nt) {
            AU b;
            b.u = *(const uint4*)(wptr + (size_t)nt * 16 * KTOT + kb * 32);
            acc[nt] = __builtin_amdgcn_mfma_f32_16x16x32_bf16(a.f, b.f, acc[nt], 0, 0, 0);
        }
    }
#pragma unroll
    for (int kb = 0; kb < 2; ++kb) {
        AU a;
        if (rowok) a.u = *(const uint4*)(xptr + kb * 32);
        else a.u = make_uint4(0, 0, 0, 0);
#pragma unroll
        for (int nt = 0; nt < 4; ++nt) {
            AU b;
            b.u = *(const uint4*)(wptr + (size_t)nt * 16 * KTOT + 512 + kb * 32);
            acc[nt] = __builtin_amdgcn_mfma_f32_16x16x32_bf16(a.f, b.f, acc[nt], 0, 0, 0);
        }
    }

#pragma unroll
    for (int nt = 0; nt < 4; ++nt) {
        int col = nt * 16 + m16;
        float bb = bias[col];
#pragma unroll
        for (int i = 0; i < 4; ++i) {
            int row = row0 + quad * 4 + i;
            if (row < NN) Out[(size_t)row * 64 + col] = acc[nt][i] + bb;
        }
    }
}

// ---------------- BN column stats + BN+ReLU (in-place, + bf16 copy) ----------------

__global__ void k_colstats(const float* __restrict__ H, float* __restrict__ stats) {
    int t = threadIdx.x;
    int col = t & 63;
    int rl = t >> 6;
    float s = 0.f, sq = 0.f;
    for (int n = blockIdx.x * 4 + rl; n < NN; n += gridDim.x * 4) {
        float v = H[(size_t)n * 64 + col];
        s += v;
        sq += v * v;
    }
    __shared__ float ss[256], sv[256];
    ss[t] = s; sv[t] = sq;
    __syncthreads();
    if (t < 128) { ss[t] += ss[t + 128]; sv[t] += sv[t + 128]; }
    __syncthreads();
    if (t < 64) {
        atomicAdd(&stats[col], ss[t] + ss[t + 64]);
        atomicAdd(&stats[64 + col], sv[t] + sv[t + 64]);
    }
}

__global__ void k_bnrelu(float* __restrict__ H, unsigned short* __restrict__ Hb,
                         const float* __restrict__ stats,
                         const float* __restrict__ gamma, const float* __restrict__ beta) {
    int idx = blockIdx.x * 256 + threadIdx.x;
    const int total = NN * DD / 4;
    if (idx >= total) return;
    int c0 = (idx & 15) * 4;
    float4 v = ((const float4*)H)[idx];
    float inv = 1.0f / (float)NN;
    float4 o;
    {
        float mu = stats[c0 + 0] * inv;
        float var = stats[64 + c0 + 0] * inv - mu * mu;
        float sc = gamma[c0 + 0] * rsqrtf(var + BN_EPS);
        float r = sc * (v.x - mu) + beta[c0 + 0];
        o.x = r > 0.f ? r : 0.f;
    }
    {
        float mu = stats[c0 + 1] * inv;
        float var = stats[64 + c0 + 1] * inv - mu * mu;
        float sc = gamma[c0 + 1] * rsqrtf(var + BN_EPS);
        float r = sc * (v.y - mu) + beta[c0 + 1];
        o.y = r > 0.f ? r : 0.f;
    }
    {
        float mu = stats[c0 + 2] * inv;
        float var = stats[64 + c0 + 2] * inv - mu * mu;
        float sc = gamma[c0 + 2] * rsqrtf(var + BN_EPS);
        float r = sc * (v.z - mu) + beta[c0 + 2];
        o.z = r > 0.f ? r : 0.f;
    }
    {
        float mu = stats[c0 + 3] * inv;
        float var = stats[64 + c0 + 3] * inv - mu * mu;
        float sc = gamma[c0 + 3] * rsqrtf(var + BN_EPS);
        float r = sc * (v.w - mu) + beta[c0 + 3];
        o.w = r > 0.f ? r : 0.f;
    }
    ((float4*)H)[idx] = o;
    ushort4 ob;
    ob.x = f32_to_bf16(o.x); ob.y = f32_to_bf16(o.y);
    ob.z = f32_to_bf16(o.z); ob.w = f32_to_bf16(o.w);
    ((ushort4*)Hb)[idx] = ob;
}

// ---------------- launch ----------------

static inline size_t alignup(size_t x) { return (x + 255) & ~(size_t)255; }

extern "C" void kernel_launch(void* const* d_in, const int* in_sizes, int n_in,
                              void* d_out, int out_size, void* d_ws, size_t ws_size,
                              hipStream_t stream) {
    const float* x      = (const float*)d_in[0];
    const int*   eidx   = (const int*)d_in[1];
    const int*   etype  = (const int*)d_in[2];
    const float* w1     = (const float*)d_in[3];
    const float* root1  = (const float*)d_in[4];
    const float* b1     = (const float*)d_in[5];
    const float* gamma1 = (const float*)d_in[6];
    const float* beta1  = (const float*)d_in[7];
    const float* w2     = (const float*)d_in[8];
    const float* root2  = (const float*)d_in[9];
    const float* b2     = (const float*)d_in[10];
    float* out = (float*)d_out;

    const int* src = eidx;
    const int* dst = eidx + EE;

    char* w = (char*)d_ws;
    int* deg    = (int*)w;            w += alignup((size_t)MM * 4);      // also cursor
    int* rowptr = (int*)w;            w += alignup((size_t)(MM + 1) * 4);
    int* part   = (int*)w;            w += alignup(1024 * 4);
    int* pscan  = (int*)w;            w += alignup(1024 * 4);
    int* rec    = (int*)w;            w += alignup((size_t)EE * 4);
    unsigned short* mean = (unsigned short*)w; w += alignup((size_t)NN * 512 * 2);
    float* h    = (float*)w;          w += alignup((size_t)NN * DD * 4);
    unsigned short* xhb = (unsigned short*)w; w += alignup((size_t)NN * DD * 2); // x_bf16, then h_bf16
    unsigned short* wct1 = (unsigned short*)w; w += alignup((size_t)64 * KTOT * 2);
    unsigned short* wct2 = (unsigned short*)w; w += alignup((size_t)64 * KTOT * 2);
    float* stats = (float*)w;         w += alignup(128 * 4);
    int* cursor = deg;                // alias (see k_scan3)

    hipMemsetAsync(deg, 0, (size_t)MM * 4, stream);
    hipMemsetAsync(stats, 0, 128 * 4, stream);

    k_prepw<<<dim3(144), dim3(256), 0, stream>>>(w1, root1, wct1);
    k_prepw<<<dim3(144), dim3(256), 0, stream>>>(w2, root2, wct2);
    k_tobf16<<<dim3(NN * DD / 4 / 256 + 1), dim3(256), 0, stream>>>(x, xhb);

    k_count<<<dim3(EE / 256), dim3(256), 0, stream>>>(dst, etype, deg);
    k_scan1<<<dim3(NBLK2), dim3(256), 0, stream>>>(deg, part);
    k_scan2<<<dim3(1), dim3(1024), 0, stream>>>(part, pscan, rowptr);
    k_scan3<<<dim3(NBLK2), dim3(256), 0, stream>>>(deg, pscan, rowptr, cursor);
    k_fill<<<dim3(EE / 256), dim3(256), 0, stream>>>(src, dst, etype, cursor, rec);

    // layer 1
    k_agg<<<dim3((NN + 3) / 4), dim3(256), 0, stream>>>(xhb, rowptr, rec, mean);
    k_gemm<<<dim3((NN + 63) / 64), dim3(256), 0, stream>>>(mean, xhb, wct1, b1, h);
    k_colstats<<<dim3(256), dim3(256), 0, stream>>>(h, stats);
    k_bnrelu<<<dim3(NN * DD / 4 / 256), dim3(256), 0, stream>>>(h, xhb, stats, gamma1, beta1);

    // layer 2 (xhb now holds bf16 of post-BN/ReLU h)
    k_agg<<<dim3((NN + 3) / 4), dim3(256), 0, stream>>>(xhb, rowptr, rec, mean);
    k_gemm<<<dim3((NN + 63) / 64), dim3(256), 0, stream>>>(mean, xhb, wct2, b2, out);
}

// Round 4
// 480.294 us; speedup vs baseline: 1.8439x; 1.2679x over previous
//
#include <hip/hip_runtime.h>
#include <hip/hip_bf16.h>

#define NN 100000
#define EE 1600000
#define RR 8
#define DD 64
#define MM (NN * RR)                 // 800000 (dst,rel) segments
#define BN_EPS 1e-5f
#define KTOT 576                     // 512 (rel) + 64 (root)

// bucket sort params: 256 dsts per bucket -> 2048 (dst,rel) keys per bucket
#define NB 391                       // ceil(100000/256)
#define EPB 8192                     // edges per block in binning kernels
#define NBIN ((EE + EPB - 1) / EPB)  // 196

typedef __bf16 bf16x8 __attribute__((ext_vector_type(8)));
typedef float  f32x4  __attribute__((ext_vector_type(4)));

static __device__ __forceinline__ unsigned short f32_to_bf16(float f) {
    unsigned int u = __float_as_uint(f);
    unsigned int r = u + 0x7FFFu + ((u >> 16) & 1u);   // RNE
    return (unsigned short)(r >> 16);
}
static __device__ __forceinline__ float bflo(unsigned int u) {
    return __uint_as_float(u << 16);
}
static __device__ __forceinline__ float bfhi(unsigned int u) {
    return __uint_as_float(u & 0xFFFF0000u);
}

// ---------------- bucketed CSR build ----------------

__global__ void k_bcount(const int* __restrict__ dst, int* __restrict__ btot) {
    __shared__ int cnt[NB];
    int t = threadIdx.x;
    for (int i = t; i < NB; i += 256) cnt[i] = 0;
    __syncthreads();
    int base = blockIdx.x * EPB;
#pragma unroll
    for (int i = 0; i < EPB / 256; ++i) {
        int e = base + i * 256 + t;
        if (e < EE) atomicAdd(&cnt[dst[e] >> 8], 1);
    }
    __syncthreads();
    for (int i = t; i < NB; i += 256)
        if (cnt[i]) atomicAdd(&btot[i], cnt[i]);
}

__global__ void k_bscan(const int* __restrict__ btot, int* __restrict__ bbase,
                        int* __restrict__ gcur, int* __restrict__ rowptr) {
    __shared__ int sd[512];
    int t = threadIdx.x;
    int v = (t < NB) ? btot[t] : 0;
    sd[t] = v;
    __syncthreads();
    for (int off = 1; off < 512; off <<= 1) {
        int x = (t >= off) ? sd[t - off] : 0;
        __syncthreads();
        sd[t] += x;
        __syncthreads();
    }
    if (t < NB) { bbase[t] = sd[t] - v; gcur[t] = sd[t] - v; }
    if (t == NB - 1) { bbase[NB] = sd[t]; rowptr[MM] = sd[t]; }
}

// bin edges into bucket-contiguous ebuf, packed: src | (localkey << 17)
__global__ void k_bin(const int* __restrict__ src, const int* __restrict__ dst,
                      const int* __restrict__ et, int* __restrict__ gcur,
                      unsigned int* __restrict__ ebuf) {
    __shared__ int cnt[NB];
    __shared__ int bas[NB];
    __shared__ int off[NB];
    int t = threadIdx.x;
    for (int i = t; i < NB; i += 256) { cnt[i] = 0; off[i] = 0; }
    __syncthreads();
    int base = blockIdx.x * EPB;
#pragma unroll
    for (int i = 0; i < EPB / 256; ++i) {
        int e = base + i * 256 + t;
        if (e < EE) atomicAdd(&cnt[dst[e] >> 8], 1);
    }
    __syncthreads();
    for (int i = t; i < NB; i += 256) {
        int c = cnt[i];
        bas[i] = c ? atomicAdd(&gcur[i], c) : 0;
    }
    __syncthreads();
#pragma unroll
    for (int i = 0; i < EPB / 256; ++i) {
        int e = base + i * 256 + t;
        if (e < EE) {
            int d = dst[e];
            int b = d >> 8;
            int lk = ((d & 255) << 3) | et[e];
            unsigned int rec0 = (unsigned int)src[e] | ((unsigned int)lk << 17);
            int p = bas[b] + atomicAdd(&off[b], 1);
            ebuf[p] = rec0;
        }
    }
}

// per-bucket: LDS histogram + scan -> rowptr; LDS cursors -> sorted rec
__global__ __launch_bounds__(256) void k_bcsr(const int* __restrict__ bbase,
                                              const unsigned int* __restrict__ ebuf,
                                              int* __restrict__ rowptr,
                                              int* __restrict__ rec) {
    __shared__ int deg[2048];
    __shared__ int part[256];
    int b = blockIdx.x, t = threadIdx.x;
    int e0 = bbase[b], e1 = bbase[b + 1];
    for (int i = t; i < 2048; i += 256) deg[i] = 0;
    __syncthreads();
    for (int e = e0 + t; e < e1; e += 256) atomicAdd(&deg[ebuf[e] >> 17], 1);
    __syncthreads();
    int loc[8];
    int s = 0;
#pragma unroll
    for (int j = 0; j < 8; ++j) { loc[j] = deg[t * 8 + j]; s += loc[j]; }
    part[t] = s;
    __syncthreads();
    for (int off = 1; off < 256; off <<= 1) {
        int x = (t >= off) ? part[t - off] : 0;
        __syncthreads();
        part[t] += x;
        __syncthreads();
    }
    int run = part[t] - s;               // exclusive prefix of this thread's 8 keys
    int keyBase = b * 2048;
#pragma unroll
    for (int j = 0; j < 8; ++j) {
        int g = keyBase + t * 8 + j;
        if (g < MM) rowptr[g] = e0 + run;
        deg[t * 8 + j] = run;            // becomes the local cursor (own entries only)
        run += loc[j];
    }
    __syncthreads();
    for (int e = e0 + t; e < e1; e += 256) {
        unsigned int v = ebuf[e];
        int lk = v >> 17;
        int pos = e0 + atomicAdd(&deg[lk], 1);
        rec[pos] = (int)(v & 0x1FFFFu);
    }
}

// ---------------- fp32 -> bf16 row conversion ----------------

__global__ void k_tobf16(const float* __restrict__ X, unsigned short* __restrict__ Xb) {
    int i = blockIdx.x * 256 + threadIdx.x;
    if (i >= NN * DD / 4) return;
    float4 v = ((const float4*)X)[i];
    ushort4 o;
    o.x = f32_to_bf16(v.x); o.y = f32_to_bf16(v.y);
    o.z = f32_to_bf16(v.z); o.w = f32_to_bf16(v.w);
    ((ushort4*)Xb)[i] = o;
}

// ---------------- aggregation: wave per dst, 8 lanes per segment ----------------
// mean layout: [N][512] bf16, k = r*64 + d.

__global__ void k_agg(const unsigned short* __restrict__ Xb,
                      const int* __restrict__ rowptr,
                      const int* __restrict__ rec,
                      unsigned short* __restrict__ mean) {
    int wv = threadIdx.x >> 6;
    int lane = threadIdx.x & 63;
    int n = blockIdx.x * 4 + wv;
    if (n >= NN) return;
    int r = lane >> 3;       // segment 0..7
    int q = lane & 7;        // dim-octet 0..7
    int e0 = rowptr[n * RR + r];
    int e1 = rowptr[n * RR + r + 1];
    float acc[8] = {0.f, 0.f, 0.f, 0.f, 0.f, 0.f, 0.f, 0.f};
    for (int e = e0; e < e1; ++e) {
        int s = rec[e];
        uint4 u = *(const uint4*)(Xb + (size_t)s * DD + q * 8);
        acc[0] += bflo(u.x); acc[1] += bfhi(u.x);
        acc[2] += bflo(u.y); acc[3] += bfhi(u.y);
        acc[4] += bflo(u.z); acc[5] += bfhi(u.z);
        acc[6] += bflo(u.w); acc[7] += bfhi(u.w);
    }
    int cnt = e1 - e0;
    float inv = 1.0f / (float)(cnt > 1 ? cnt : 1);
    uint4 o;
    o.x = (unsigned)f32_to_bf16(acc[0] * inv) | ((unsigned)f32_to_bf16(acc[1] * inv) << 16);
    o.y = (unsigned)f32_to_bf16(acc[2] * inv) | ((unsigned)f32_to_bf16(acc[3] * inv) << 16);
    o.z = (unsigned)f32_to_bf16(acc[4] * inv) | ((unsigned)f32_to_bf16(acc[5] * inv) << 16);
    o.w = (unsigned)f32_to_bf16(acc[6] * inv) | ((unsigned)f32_to_bf16(acc[7] * inv) << 16);
    *(uint4*)(mean + (size_t)n * 512 + r * 64 + q * 8) = o;
}

// ---------------- weight prep: WcT[64][576] bf16, k = r*64+d (+root tail) ----------------

__global__ void k_prepw(const float* __restrict__ W, const float* __restrict__ Root,
                        unsigned short* __restrict__ WcT) {
    int i = blockIdx.x * 256 + threadIdx.x;
    if (i >= 64 * KTOT) return;
    int o = i / KTOT;
    int k = i - o * KTOT;
    float v;
    if (k < 512) v = W[(size_t)(k >> 6) * 4096 + (k & 63) * 64 + o];
    else         v = Root[(k - 512) * 64 + o];
    WcT[(size_t)o * KTOT + k] = f32_to_bf16(v);
}

// ---------------- MFMA GEMM: out[N][64] = [mean | Xb] @ Wc + bias ----------------

__global__ __launch_bounds__(256) void k_gemm(const unsigned short* __restrict__ meanB,
                                              const unsigned short* __restrict__ Xb,
                                              const unsigned short* __restrict__ WcT,
                                              const float* __restrict__ bias,
                                              float* __restrict__ Out) {
    int t = threadIdx.x;
    int wv = t >> 6, lane = t & 63;
    int quad = lane >> 4, m16 = lane & 15;
    int row0 = blockIdx.x * 64 + wv * 16;
    int arow = row0 + m16;
    bool rowok = arow < NN;

    union AU { uint4 u; bf16x8 f; };
    f32x4 acc[4] = {{0.f,0.f,0.f,0.f},{0.f,0.f,0.f,0.f},{0.f,0.f,0.f,0.f},{0.f,0.f,0.f,0.f}};

    const unsigned short* aptr = meanB + (size_t)arow * 512 + quad * 8;
    const unsigned short* xptr = Xb + (size_t)arow * DD + quad * 8;
    const unsigned short* wptr = WcT + (size_t)m16 * KTOT + quad * 8;

#pragma unroll
    for (int kb = 0; kb < 16; ++kb) {
        AU a;
        if (rowok) a.u = *(const uint4*)(aptr + kb * 32);
        else a.u = make_uint4(0, 0, 0, 0);
#pragma unroll
        for (int nt = 0; nt < 4; ++nt) {
            AU b;
            b.u = *(const uint4*)(wptr + (size_t)nt * 16 * KTOT + kb * 32);
            acc[nt] = __builtin_amdgcn_mfma_f32_16x16x32_bf16(a.f, b.f, acc[nt], 0, 0, 0);
        }
    }
#pragma unroll
    for (int kb = 0; kb < 2; ++kb) {
        AU a;
        if (rowok) a.u = *(const uint4*)(xptr + kb * 32);
        else a.u = make_uint4(0, 0, 0, 0);
#pragma unroll
        for (int nt = 0; nt < 4; ++nt) {
            AU b;
            b.u = *(const uint4*)(wptr + (size_t)nt * 16 * KTOT + 512 + kb * 32);
            acc[nt] = __builtin_amdgcn_mfma_f32_16x16x32_bf16(a.f, b.f, acc[nt], 0, 0, 0);
        }
    }

#pragma unroll
    for (int nt = 0; nt < 4; ++nt) {
        int col = nt * 16 + m16;
        float bb = bias[col];
#pragma unroll
        for (int i = 0; i < 4; ++i) {
            int row = row0 + quad * 4 + i;
            if (row < NN) Out[(size_t)row * 64 + col] = acc[nt][i] + bb;
        }
    }
}

// ---------------- BN column stats + BN+ReLU (in-place, + bf16 copy) ----------------

__global__ void k_colstats(const float* __restrict__ H, float* __restrict__ stats) {
    int t = threadIdx.x;
    int col = t & 63;
    int rl = t >> 6;
    float s = 0.f, sq = 0.f;
    for (int n = blockIdx.x * 4 + rl; n < NN; n += gridDim.x * 4) {
        float v = H[(size_t)n * 64 + col];
        s += v;
        sq += v * v;
    }
    __shared__ float ss[256], sv[256];
    ss[t] = s; sv[t] = sq;
    __syncthreads();
    if (t < 128) { ss[t] += ss[t + 128]; sv[t] += sv[t + 128]; }
    __syncthreads();
    if (t < 64) {
        atomicAdd(&stats[col], ss[t] + ss[t + 64]);
        atomicAdd(&stats[64 + col], sv[t] + sv[t + 64]);
    }
}

__global__ void k_bnrelu(float* __restrict__ H, unsigned short* __restrict__ Hb,
                         const float* __restrict__ stats,
                         const float* __restrict__ gamma, const float* __restrict__ beta) {
    int idx = blockIdx.x * 256 + threadIdx.x;
    const int total = NN * DD / 4;
    if (idx >= total) return;
    int c0 = (idx & 15) * 4;
    float4 v = ((const float4*)H)[idx];
    float inv = 1.0f / (float)NN;
    float4 o;
    {
        float mu = stats[c0 + 0] * inv;
        float var = stats[64 + c0 + 0] * inv - mu * mu;
        float sc = gamma[c0 + 0] * rsqrtf(var + BN_EPS);
        float r = sc * (v.x - mu) + beta[c0 + 0];
        o.x = r > 0.f ? r : 0.f;
    }
    {
        float mu = stats[c0 + 1] * inv;
        float var = stats[64 + c0 + 1] * inv - mu * mu;
        float sc = gamma[c0 + 1] * rsqrtf(var + BN_EPS);
        float r = sc * (v.y - mu) + beta[c0 + 1];
        o.y = r > 0.f ? r : 0.f;
    }
    {
        float mu = stats[c0 + 2] * inv;
        float var = stats[64 + c0 + 2] * inv - mu * mu;
        float sc = gamma[c0 + 2] * rsqrtf(var + BN_EPS);
        float r = sc * (v.z - mu) + beta[c0 + 2];
        o.z = r > 0.f ? r : 0.f;
    }
    {
        float mu = stats[c0 + 3] * inv;
        float var = stats[64 + c0 + 3] * inv - mu * mu;
        float sc = gamma[c0 + 3] * rsqrtf(var + BN_EPS);
        float r = sc * (v.w - mu) + beta[c0 + 3];
        o.w = r > 0.f ? r : 0.f;
    }
    ((float4*)H)[idx] = o;
    ushort4 ob;
    ob.x = f32_to_bf16(o.x); ob.y = f32_to_bf16(o.y);
    ob.z = f32_to_bf16(o.z); ob.w = f32_to_bf16(o.w);
    ((ushort4*)Hb)[idx] = ob;
}

// ---------------- launch ----------------

static inline size_t alignup(size_t x) { return (x + 255) & ~(size_t)255; }

extern "C" void kernel_launch(void* const* d_in, const int* in_sizes, int n_in,
                              void* d_out, int out_size, void* d_ws, size_t ws_size,
                              hipStream_t stream) {
    const float* x      = (const float*)d_in[0];
    const int*   eidx   = (const int*)d_in[1];
    const int*   etype  = (const int*)d_in[2];
    const float* w1     = (const float*)d_in[3];
    const float* root1  = (const float*)d_in[4];
    const float* b1     = (const float*)d_in[5];
    const float* gamma1 = (const float*)d_in[6];
    const float* beta1  = (const float*)d_in[7];
    const float* w2     = (const float*)d_in[8];
    const float* root2  = (const float*)d_in[9];
    const float* b2     = (const float*)d_in[10];
    float* out = (float*)d_out;

    const int* src = eidx;
    const int* dst = eidx + EE;

    char* w = (char*)d_ws;
    int* rowptr = (int*)w;            w += alignup((size_t)(MM + 1) * 4);
    int* btot   = (int*)w;            w += alignup(512 * 4);
    int* bbase  = (int*)w;            w += alignup(512 * 4);
    int* gcur   = (int*)w;            w += alignup(512 * 4);
    int* rec    = (int*)w;            w += alignup((size_t)EE * 4);
    unsigned short* mean = (unsigned short*)w; w += alignup((size_t)NN * 512 * 2);
    float* h    = (float*)w;          w += alignup((size_t)NN * DD * 4);
    unsigned short* xhb = (unsigned short*)w; w += alignup((size_t)NN * DD * 2);
    unsigned short* wct1 = (unsigned short*)w; w += alignup((size_t)64 * KTOT * 2);
    unsigned short* wct2 = (unsigned short*)w; w += alignup((size_t)64 * KTOT * 2);
    float* stats = (float*)w;         w += alignup(128 * 4);
    unsigned int* ebuf = (unsigned int*)mean;   // alias: dead before k_agg writes mean

    hipMemsetAsync(btot, 0, 512 * 4, stream);
    hipMemsetAsync(stats, 0, 128 * 4, stream);

    k_prepw<<<dim3(144), dim3(256), 0, stream>>>(w1, root1, wct1);
    k_prepw<<<dim3(144), dim3(256), 0, stream>>>(w2, root2, wct2);
    k_tobf16<<<dim3(NN * DD / 4 / 256 + 1), dim3(256), 0, stream>>>(x, xhb);

    // bucketed CSR build
    k_bcount<<<dim3(NBIN), dim3(256), 0, stream>>>(dst, btot);
    k_bscan<<<dim3(1), dim3(512), 0, stream>>>(btot, bbase, gcur, rowptr);
    k_bin<<<dim3(NBIN), dim3(256), 0, stream>>>(src, dst, etype, gcur, ebuf);
    k_bcsr<<<dim3(NB), dim3(256), 0, stream>>>(bbase, ebuf, rowptr, rec);

    // layer 1
    k_agg<<<dim3((NN + 3) / 4), dim3(256), 0, stream>>>(xhb, rowptr, rec, mean);
    k_gemm<<<dim3((NN + 63) / 64), dim3(256), 0, stream>>>(mean, xhb, wct1, b1, h);
    k_colstats<<<dim3(256), dim3(256), 0, stream>>>(h, stats);
    k_bnrelu<<<dim3(NN * DD / 4 / 256), dim3(256), 0, stream>>>(h, xhb, stats, gamma1, beta1);

    // layer 2 (xhb now holds bf16 of post-BN/ReLU h)
    k_agg<<<dim3((NN + 3) / 4), dim3(256), 0, stream>>>(xhb, rowptr, rec, mean);
    k_gemm<<<dim3((NN + 63) / 64), dim3(256), 0, stream>>>(mean, xhb, wct2, b2, out);
}

// Round 5
// 422.834 us; speedup vs baseline: 2.0945x; 1.1359x over previous
//
#include <hip/hip_runtime.h>
#include <hip/hip_bf16.h>

#define NN 100000
#define EE 1600000
#define RR 8
#define DD 64
#define MM (NN * RR)                 // 800000 (dst,rel) segments
#define BN_EPS 1e-5f
#define KTOT 576                     // 512 (rel) + 64 (root)

// bucket sort params: 256 dsts per bucket -> 2048 (dst,rel) keys per bucket
#define NB 391                       // ceil(100000/256)
#define EPB 8192                     // edges per block in binning kernels
#define NBIN ((EE + EPB - 1) / EPB)  // 196

typedef __bf16 bf16x8 __attribute__((ext_vector_type(8)));
typedef float  f32x4  __attribute__((ext_vector_type(4)));

static __device__ __forceinline__ unsigned short f32_to_bf16(float f) {
    unsigned int u = __float_as_uint(f);
    unsigned int r = u + 0x7FFFu + ((u >> 16) & 1u);   // RNE
    return (unsigned short)(r >> 16);
}
static __device__ __forceinline__ float bflo(unsigned int u) {
    return __uint_as_float(u << 16);
}
static __device__ __forceinline__ float bfhi(unsigned int u) {
    return __uint_as_float(u & 0xFFFF0000u);
}

// ---------------- bucketed CSR build ----------------

__global__ void k_bcount(const int* __restrict__ dst, int* __restrict__ btot) {
    __shared__ int cnt[NB];
    int t = threadIdx.x;
    for (int i = t; i < NB; i += 256) cnt[i] = 0;
    __syncthreads();
    int base = blockIdx.x * EPB;
#pragma unroll
    for (int i = 0; i < EPB / 256; ++i) {
        int e = base + i * 256 + t;
        if (e < EE) atomicAdd(&cnt[dst[e] >> 8], 1);
    }
    __syncthreads();
    for (int i = t; i < NB; i += 256)
        if (cnt[i]) atomicAdd(&btot[i], cnt[i]);
}

__global__ void k_bscan(const int* __restrict__ btot, int* __restrict__ bbase,
                        int* __restrict__ gcur, int* __restrict__ rowptr) {
    __shared__ int sd[512];
    int t = threadIdx.x;
    int v = (t < NB) ? btot[t] : 0;
    sd[t] = v;
    __syncthreads();
    for (int off = 1; off < 512; off <<= 1) {
        int x = (t >= off) ? sd[t - off] : 0;
        __syncthreads();
        sd[t] += x;
        __syncthreads();
    }
    if (t < NB) { bbase[t] = sd[t] - v; gcur[t] = sd[t] - v; }
    if (t == NB - 1) { bbase[NB] = sd[t]; rowptr[MM] = sd[t]; }
}

// bin edges into bucket-contiguous ebuf, packed: src | (localkey << 17)
__global__ void k_bin(const int* __restrict__ src, const int* __restrict__ dst,
                      const int* __restrict__ et, int* __restrict__ gcur,
                      unsigned int* __restrict__ ebuf) {
    __shared__ int cnt[NB];
    __shared__ int bas[NB];
    __shared__ int off[NB];
    int t = threadIdx.x;
    for (int i = t; i < NB; i += 256) { cnt[i] = 0; off[i] = 0; }
    __syncthreads();
    int base = blockIdx.x * EPB;
#pragma unroll
    for (int i = 0; i < EPB / 256; ++i) {
        int e = base + i * 256 + t;
        if (e < EE) atomicAdd(&cnt[dst[e] >> 8], 1);
    }
    __syncthreads();
    for (int i = t; i < NB; i += 256) {
        int c = cnt[i];
        bas[i] = c ? atomicAdd(&gcur[i], c) : 0;
    }
    __syncthreads();
#pragma unroll
    for (int i = 0; i < EPB / 256; ++i) {
        int e = base + i * 256 + t;
        if (e < EE) {
            int d = dst[e];
            int b = d >> 8;
            int lk = ((d & 255) << 3) | et[e];
            unsigned int rec0 = (unsigned int)src[e] | ((unsigned int)lk << 17);
            int p = bas[b] + atomicAdd(&off[b], 1);
            ebuf[p] = rec0;
        }
    }
}

// per-bucket: LDS histogram + scan -> rowptr; LDS cursors -> sorted rec
__global__ __launch_bounds__(256) void k_bcsr(const int* __restrict__ bbase,
                                              const unsigned int* __restrict__ ebuf,
                                              int* __restrict__ rowptr,
                                              int* __restrict__ rec) {
    __shared__ int deg[2048];
    __shared__ int part[256];
    int b = blockIdx.x, t = threadIdx.x;
    int e0 = bbase[b], e1 = bbase[b + 1];
    for (int i = t; i < 2048; i += 256) deg[i] = 0;
    __syncthreads();
    for (int e = e0 + t; e < e1; e += 256) atomicAdd(&deg[ebuf[e] >> 17], 1);
    __syncthreads();
    int loc[8];
    int s = 0;
#pragma unroll
    for (int j = 0; j < 8; ++j) { loc[j] = deg[t * 8 + j]; s += loc[j]; }
    part[t] = s;
    __syncthreads();
    for (int off = 1; off < 256; off <<= 1) {
        int x = (t >= off) ? part[t - off] : 0;
        __syncthreads();
        part[t] += x;
        __syncthreads();
    }
    int run = part[t] - s;
    int keyBase = b * 2048;
#pragma unroll
    for (int j = 0; j < 8; ++j) {
        int g = keyBase + t * 8 + j;
        if (g < MM) rowptr[g] = e0 + run;
        deg[t * 8 + j] = run;
        run += loc[j];
    }
    __syncthreads();
    for (int e = e0 + t; e < e1; e += 256) {
        unsigned int v = ebuf[e];
        int lk = v >> 17;
        int pos = e0 + atomicAdd(&deg[lk], 1);
        rec[pos] = (int)(v & 0x1FFFFu);
    }
}

// ---------------- fp32 -> bf16 row conversion ----------------

__global__ void k_tobf16(const float* __restrict__ X, unsigned short* __restrict__ Xb) {
    int i = blockIdx.x * 256 + threadIdx.x;
    if (i >= NN * DD / 4) return;
    float4 v = ((const float4*)X)[i];
    ushort4 o;
    o.x = f32_to_bf16(v.x); o.y = f32_to_bf16(v.y);
    o.z = f32_to_bf16(v.z); o.w = f32_to_bf16(v.w);
    ((ushort4*)Xb)[i] = o;
}

// ---------------- aggregation: wave per dst, 8 lanes per segment ----------------
// mean layout: [N][512] bf16, k = r*64 + d. Edge loop unrolled x2 so the
// rec->Xb dependent chains of consecutive edges overlap.

__global__ void k_agg(const unsigned short* __restrict__ Xb,
                      const int* __restrict__ rowptr,
                      const int* __restrict__ rec,
                      unsigned short* __restrict__ mean) {
    int wv = threadIdx.x >> 6;
    int lane = threadIdx.x & 63;
    int n = blockIdx.x * 4 + wv;
    if (n >= NN) return;
    int r = lane >> 3;       // segment 0..7
    int q = lane & 7;        // dim-octet 0..7
    int e0 = rowptr[n * RR + r];
    int e1 = rowptr[n * RR + r + 1];
    float a0[8] = {0.f, 0.f, 0.f, 0.f, 0.f, 0.f, 0.f, 0.f};
    float a1[8] = {0.f, 0.f, 0.f, 0.f, 0.f, 0.f, 0.f, 0.f};
    int e = e0;
    for (; e + 1 < e1; e += 2) {
        int s0 = rec[e];
        int s1 = rec[e + 1];
        uint4 u0 = *(const uint4*)(Xb + (size_t)s0 * DD + q * 8);
        uint4 u1 = *(const uint4*)(Xb + (size_t)s1 * DD + q * 8);
        a0[0] += bflo(u0.x); a0[1] += bfhi(u0.x);
        a0[2] += bflo(u0.y); a0[3] += bfhi(u0.y);
        a0[4] += bflo(u0.z); a0[5] += bfhi(u0.z);
        a0[6] += bflo(u0.w); a0[7] += bfhi(u0.w);
        a1[0] += bflo(u1.x); a1[1] += bfhi(u1.x);
        a1[2] += bflo(u1.y); a1[3] += bfhi(u1.y);
        a1[4] += bflo(u1.z); a1[5] += bfhi(u1.z);
        a1[6] += bflo(u1.w); a1[7] += bfhi(u1.w);
    }
    if (e < e1) {
        int s0 = rec[e];
        uint4 u0 = *(const uint4*)(Xb + (size_t)s0 * DD + q * 8);
        a0[0] += bflo(u0.x); a0[1] += bfhi(u0.x);
        a0[2] += bflo(u0.y); a0[3] += bfhi(u0.y);
        a0[4] += bflo(u0.z); a0[5] += bfhi(u0.z);
        a0[6] += bflo(u0.w); a0[7] += bfhi(u0.w);
    }
    int cnt = e1 - e0;
    float inv = 1.0f / (float)(cnt > 1 ? cnt : 1);
    uint4 o;
    o.x = (unsigned)f32_to_bf16((a0[0] + a1[0]) * inv) | ((unsigned)f32_to_bf16((a0[1] + a1[1]) * inv) << 16);
    o.y = (unsigned)f32_to_bf16((a0[2] + a1[2]) * inv) | ((unsigned)f32_to_bf16((a0[3] + a1[3]) * inv) << 16);
    o.z = (unsigned)f32_to_bf16((a0[4] + a1[4]) * inv) | ((unsigned)f32_to_bf16((a0[5] + a1[5]) * inv) << 16);
    o.w = (unsigned)f32_to_bf16((a0[6] + a1[6]) * inv) | ((unsigned)f32_to_bf16((a0[7] + a1[7]) * inv) << 16);
    *(uint4*)(mean + (size_t)n * 512 + r * 64 + q * 8) = o;
}

// ---------------- weight prep: WcT[64][576] bf16, k = r*64+d (+root tail) ----------------

__global__ void k_prepw(const float* __restrict__ W, const float* __restrict__ Root,
                        unsigned short* __restrict__ WcT) {
    int i = blockIdx.x * 256 + threadIdx.x;
    if (i >= 64 * KTOT) return;
    int o = i / KTOT;
    int k = i - o * KTOT;
    float v;
    if (k < 512) v = W[(size_t)(k >> 6) * 4096 + (k & 63) * 64 + o];
    else         v = Root[(k - 512) * 64 + o];
    WcT[(size_t)o * KTOT + k] = f32_to_bf16(v);
}

// ---------------- MFMA GEMM: out[N][64] = [mean | Xb] @ Wc + bias ----------------
// wave: 32 rows x 64 cols = 2 row-tiles sharing each B fragment.
// per k-step: 2 A-loads + 4 B-loads + 8 MFMA.

__global__ __launch_bounds__(256) void k_gemm(const unsigned short* __restrict__ meanB,
                                              const unsigned short* __restrict__ Xb,
                                              const unsigned short* __restrict__ WcT,
                                              const float* __restrict__ bias,
                                              float* __restrict__ Out) {
    int t = threadIdx.x;
    int wv = t >> 6, lane = t & 63;
    int quad = lane >> 4, m16 = lane & 15;
    int row0 = blockIdx.x * 128 + wv * 32;
    int r0 = row0 + m16;
    int r1 = row0 + 16 + m16;
    bool ok0 = r0 < NN, ok1 = r1 < NN;

    union AU { uint4 u; bf16x8 f; };
    f32x4 acc[2][4];
#pragma unroll
    for (int i = 0; i < 2; ++i)
#pragma unroll
        for (int j = 0; j < 4; ++j) acc[i][j] = (f32x4){0.f, 0.f, 0.f, 0.f};

    const unsigned short* a0p = meanB + (size_t)r0 * 512 + quad * 8;
    const unsigned short* a1p = meanB + (size_t)r1 * 512 + quad * 8;
    const unsigned short* x0p = Xb + (size_t)r0 * DD + quad * 8;
    const unsigned short* x1p = Xb + (size_t)r1 * DD + quad * 8;
    const unsigned short* wp  = WcT + (size_t)m16 * KTOT + quad * 8;

#pragma unroll
    for (int kb = 0; kb < 16; ++kb) {
        AU av0, av1, bv[4];
        if (ok0) av0.u = *(const uint4*)(a0p + kb * 32); else av0.u = make_uint4(0,0,0,0);
        if (ok1) av1.u = *(const uint4*)(a1p + kb * 32); else av1.u = make_uint4(0,0,0,0);
#pragma unroll
        for (int nt = 0; nt < 4; ++nt)
            bv[nt].u = *(const uint4*)(wp + (size_t)nt * 16 * KTOT + kb * 32);
#pragma unroll
        for (int nt = 0; nt < 4; ++nt) {
            acc[0][nt] = __builtin_amdgcn_mfma_f32_16x16x32_bf16(av0.f, bv[nt].f, acc[0][nt], 0, 0, 0);
            acc[1][nt] = __builtin_amdgcn_mfma_f32_16x16x32_bf16(av1.f, bv[nt].f, acc[1][nt], 0, 0, 0);
        }
    }
#pragma unroll
    for (int kb = 0; kb < 2; ++kb) {
        AU av0, av1, bv[4];
        if (ok0) av0.u = *(const uint4*)(x0p + kb * 32); else av0.u = make_uint4(0,0,0,0);
        if (ok1) av1.u = *(const uint4*)(x1p + kb * 32); else av1.u = make_uint4(0,0,0,0);
#pragma unroll
        for (int nt = 0; nt < 4; ++nt)
            bv[nt].u = *(const uint4*)(wp + (size_t)nt * 16 * KTOT + 512 + kb * 32);
#pragma unroll
        for (int nt = 0; nt < 4; ++nt) {
            acc[0][nt] = __builtin_amdgcn_mfma_f32_16x16x32_bf16(av0.f, bv[nt].f, acc[0][nt], 0, 0, 0);
            acc[1][nt] = __builtin_amdgcn_mfma_f32_16x16x32_bf16(av1.f, bv[nt].f, acc[1][nt], 0, 0, 0);
        }
    }

#pragma unroll
    for (int rt = 0; rt < 2; ++rt) {
#pragma unroll
        for (int nt = 0; nt < 4; ++nt) {
            int col = nt * 16 + m16;
            float bb = bias[col];
#pragma unroll
            for (int i = 0; i < 4; ++i) {
                int row = row0 + rt * 16 + quad * 4 + i;
                if (row < NN) Out[(size_t)row * 64 + col] = acc[rt][nt][i] + bb;
            }
        }
    }
}

// ---------------- BN column stats + BN+ReLU (in-place, + bf16 copy) ----------------

__global__ void k_colstats(const float* __restrict__ H, float* __restrict__ stats) {
    int t = threadIdx.x;
    int col = t & 63;
    int rl = t >> 6;
    float s = 0.f, sq = 0.f;
    for (int n = blockIdx.x * 4 + rl; n < NN; n += gridDim.x * 4) {
        float v = H[(size_t)n * 64 + col];
        s += v;
        sq += v * v;
    }
    __shared__ float ss[256], sv[256];
    ss[t] = s; sv[t] = sq;
    __syncthreads();
    if (t < 128) { ss[t] += ss[t + 128]; sv[t] += sv[t + 128]; }
    __syncthreads();
    if (t < 64) {
        atomicAdd(&stats[col], ss[t] + ss[t + 64]);
        atomicAdd(&stats[64 + col], sv[t] + sv[t + 64]);
    }
}

__global__ void k_bnrelu(float* __restrict__ H, unsigned short* __restrict__ Hb,
                         const float* __restrict__ stats,
                         const float* __restrict__ gamma, const float* __restrict__ beta) {
    int idx = blockIdx.x * 256 + threadIdx.x;
    const int total = NN * DD / 4;
    if (idx >= total) return;
    int c0 = (idx & 15) * 4;
    float4 v = ((const float4*)H)[idx];
    float inv = 1.0f / (float)NN;
    float4 o;
    {
        float mu = stats[c0 + 0] * inv;
        float var = stats[64 + c0 + 0] * inv - mu * mu;
        float sc = gamma[c0 + 0] * rsqrtf(var + BN_EPS);
        float r = sc * (v.x - mu) + beta[c0 + 0];
        o.x = r > 0.f ? r : 0.f;
    }
    {
        float mu = stats[c0 + 1] * inv;
        float var = stats[64 + c0 + 1] * inv - mu * mu;
        float sc = gamma[c0 + 1] * rsqrtf(var + BN_EPS);
        float r = sc * (v.y - mu) + beta[c0 + 1];
        o.y = r > 0.f ? r : 0.f;
    }
    {
        float mu = stats[c0 + 2] * inv;
        float var = stats[64 + c0 + 2] * inv - mu * mu;
        float sc = gamma[c0 + 2] * rsqrtf(var + BN_EPS);
        float r = sc * (v.z - mu) + beta[c0 + 2];
        o.z = r > 0.f ? r : 0.f;
    }
    {
        float mu = stats[c0 + 3] * inv;
        float var = stats[64 + c0 + 3] * inv - mu * mu;
        float sc = gamma[c0 + 3] * rsqrtf(var + BN_EPS);
        float r = sc * (v.w - mu) + beta[c0 + 3];
        o.w = r > 0.f ? r : 0.f;
    }
    ((float4*)H)[idx] = o;
    ushort4 ob;
    ob.x = f32_to_bf16(o.x); ob.y = f32_to_bf16(o.y);
    ob.z = f32_to_bf16(o.z); ob.w = f32_to_bf16(o.w);
    ((ushort4*)Hb)[idx] = ob;
}

// ---------------- launch ----------------

static inline size_t alignup(size_t x) { return (x + 255) & ~(size_t)255; }

extern "C" void kernel_launch(void* const* d_in, const int* in_sizes, int n_in,
                              void* d_out, int out_size, void* d_ws, size_t ws_size,
                              hipStream_t stream) {
    const float* x      = (const float*)d_in[0];
    const int*   eidx   = (const int*)d_in[1];
    const int*   etype  = (const int*)d_in[2];
    const float* w1     = (const float*)d_in[3];
    const float* root1  = (const float*)d_in[4];
    const float* b1     = (const float*)d_in[5];
    const float* gamma1 = (const float*)d_in[6];
    const float* beta1  = (const float*)d_in[7];
    const float* w2     = (const float*)d_in[8];
    const float* root2  = (const float*)d_in[9];
    const float* b2     = (const float*)d_in[10];
    float* out = (float*)d_out;

    const int* src = eidx;
    const int* dst = eidx + EE;

    char* w = (char*)d_ws;
    int* rowptr = (int*)w;            w += alignup((size_t)(MM + 1) * 4);
    int* btot   = (int*)w;            w += alignup(512 * 4);
    int* bbase  = (int*)w;            w += alignup(512 * 4);
    int* gcur   = (int*)w;            w += alignup(512 * 4);
    int* rec    = (int*)w;            w += alignup((size_t)EE * 4);
    unsigned short* mean = (unsigned short*)w; w += alignup((size_t)NN * 512 * 2);
    float* h    = (float*)w;          w += alignup((size_t)NN * DD * 4);
    unsigned short* xhb = (unsigned short*)w; w += alignup((size_t)NN * DD * 2);
    unsigned short* wct1 = (unsigned short*)w; w += alignup((size_t)64 * KTOT * 2);
    unsigned short* wct2 = (unsigned short*)w; w += alignup((size_t)64 * KTOT * 2);
    float* stats = (float*)w;         w += alignup(128 * 4);
    unsigned int* ebuf = (unsigned int*)mean;   // alias: dead before k_agg writes mean

    hipMemsetAsync(btot, 0, 512 * 4, stream);
    hipMemsetAsync(stats, 0, 128 * 4, stream);

    k_prepw<<<dim3(144), dim3(256), 0, stream>>>(w1, root1, wct1);
    k_prepw<<<dim3(144), dim3(256), 0, stream>>>(w2, root2, wct2);
    k_tobf16<<<dim3(NN * DD / 4 / 256 + 1), dim3(256), 0, stream>>>(x, xhb);

    // bucketed CSR build
    k_bcount<<<dim3(NBIN), dim3(256), 0, stream>>>(dst, btot);
    k_bscan<<<dim3(1), dim3(512), 0, stream>>>(btot, bbase, gcur, rowptr);
    k_bin<<<dim3(NBIN), dim3(256), 0, stream>>>(src, dst, etype, gcur, ebuf);
    k_bcsr<<<dim3(NB), dim3(256), 0, stream>>>(bbase, ebuf, rowptr, rec);

    // layer 1
    k_agg<<<dim3((NN + 3) / 4), dim3(256), 0, stream>>>(xhb, rowptr, rec, mean);
    k_gemm<<<dim3((NN + 127) / 128), dim3(256), 0, stream>>>(mean, xhb, wct1, b1, h);
    k_colstats<<<dim3(256), dim3(256), 0, stream>>>(h, stats);
    k_bnrelu<<<dim3(NN * DD / 4 / 256), dim3(256), 0, stream>>>(h, xhb, stats, gamma1, beta1);

    // layer 2 (xhb now holds bf16 of post-BN/ReLU h)
    k_agg<<<dim3((NN + 3) / 4), dim3(256), 0, stream>>>(xhb, rowptr, rec, mean);
    k_gemm<<<dim3((NN + 127) / 128), dim3(256), 0, stream>>>(mean, xhb, wct2, b2, out);
}

// Round 7
// 377.403 us; speedup vs baseline: 2.3466x; 1.1204x over previous
//
#include <hip/hip_runtime.h>
#include <hip/hip_bf16.h>

#define NN 100000
#define EE 1600000
#define RR 8
#define DD 64
#define MM (NN * RR)                 // 800000 (dst,rel) segments
#define BN_EPS 1e-5f
#define KTOT 576                     // 512 (rel) + 64 (root)
#define BSTRIDE 584                  // LDS B row pitch in shorts (292 words % 32 = 4)

// bucket sort params: 256 dsts per bucket -> 2048 (dst,rel) keys per bucket
#define NB 391                       // ceil(100000/256)
#define EPB 8192                     // edges per block in binning kernels
#define NBIN ((EE + EPB - 1) / EPB)  // 196

typedef __bf16 bf16x8 __attribute__((ext_vector_type(8)));
typedef float  f32x4  __attribute__((ext_vector_type(4)));

static __device__ __forceinline__ unsigned short f32_to_bf16(float f) {
    unsigned int u = __float_as_uint(f);
    unsigned int r = u + 0x7FFFu + ((u >> 16) & 1u);   // RNE
    return (unsigned short)(r >> 16);
}
static __device__ __forceinline__ float bflo(unsigned int u) {
    return __uint_as_float(u << 16);
}
static __device__ __forceinline__ float bfhi(unsigned int u) {
    return __uint_as_float(u & 0xFFFF0000u);
}

// ---------------- bucketed CSR build ----------------

__global__ void k_bcount(const int* __restrict__ dst, int* __restrict__ btot) {
    __shared__ int cnt[NB];
    int t = threadIdx.x;
    for (int i = t; i < NB; i += 256) cnt[i] = 0;
    __syncthreads();
    int base = blockIdx.x * EPB;
#pragma unroll
    for (int i = 0; i < EPB / 256; ++i) {
        int e = base + i * 256 + t;
        if (e < EE) atomicAdd(&cnt[dst[e] >> 8], 1);
    }
    __syncthreads();
    for (int i = t; i < NB; i += 256)
        if (cnt[i]) atomicAdd(&btot[i], cnt[i]);
}

__global__ void k_bscan(const int* __restrict__ btot, int* __restrict__ bbase,
                        int* __restrict__ gcur, int* __restrict__ rowptr) {
    __shared__ int sd[512];
    int t = threadIdx.x;
    int v = (t < NB) ? btot[t] : 0;
    sd[t] = v;
    __syncthreads();
    for (int off = 1; off < 512; off <<= 1) {
        int x = (t >= off) ? sd[t - off] : 0;
        __syncthreads();
        sd[t] += x;
        __syncthreads();
    }
    if (t < NB) { bbase[t] = sd[t] - v; gcur[t] = sd[t] - v; }
    if (t == NB - 1) { bbase[NB] = sd[t]; rowptr[MM] = sd[t]; }
}

// bin edges into bucket-contiguous ebuf, packed: src | (localkey << 17)
__global__ void k_bin(const int* __restrict__ src, const int* __restrict__ dst,
                      const int* __restrict__ et, int* __restrict__ gcur,
                      unsigned int* __restrict__ ebuf) {
    __shared__ int cnt[NB];
    __shared__ int bas[NB];
    __shared__ int off[NB];
    int t = threadIdx.x;
    for (int i = t; i < NB; i += 256) { cnt[i] = 0; off[i] = 0; }
    __syncthreads();
    int base = blockIdx.x * EPB;
#pragma unroll
    for (int i = 0; i < EPB / 256; ++i) {
        int e = base + i * 256 + t;
        if (e < EE) atomicAdd(&cnt[dst[e] >> 8], 1);
    }
    __syncthreads();
    for (int i = t; i < NB; i += 256) {
        int c = cnt[i];
        bas[i] = c ? atomicAdd(&gcur[i], c) : 0;
    }
    __syncthreads();
#pragma unroll
    for (int i = 0; i < EPB / 256; ++i) {
        int e = base + i * 256 + t;
        if (e < EE) {
            int d = dst[e];
            int b = d >> 8;
            int lk = ((d & 255) << 3) | et[e];
            unsigned int rec0 = (unsigned int)src[e] | ((unsigned int)lk << 17);
            int p = bas[b] + atomicAdd(&off[b], 1);
            ebuf[p] = rec0;
        }
    }
}

// per-bucket: LDS histogram + scan -> rowptr; LDS cursors -> sorted rec
__global__ __launch_bounds__(256) void k_bcsr(const int* __restrict__ bbase,
                                              const unsigned int* __restrict__ ebuf,
                                              int* __restrict__ rowptr,
                                              int* __restrict__ rec) {
    __shared__ int deg[2048];
    __shared__ int part[256];
    int b = blockIdx.x, t = threadIdx.x;
    int e0 = bbase[b], e1 = bbase[b + 1];
    for (int i = t; i < 2048; i += 256) deg[i] = 0;
    __syncthreads();
    for (int e = e0 + t; e < e1; e += 256) atomicAdd(&deg[ebuf[e] >> 17], 1);
    __syncthreads();
    int loc[8];
    int s = 0;
#pragma unroll
    for (int j = 0; j < 8; ++j) { loc[j] = deg[t * 8 + j]; s += loc[j]; }
    part[t] = s;
    __syncthreads();
    for (int off = 1; off < 256; off <<= 1) {
        int x = (t >= off) ? part[t - off] : 0;
        __syncthreads();
        part[t] += x;
        __syncthreads();
    }
    int run = part[t] - s;
    int keyBase = b * 2048;
#pragma unroll
    for (int j = 0; j < 8; ++j) {
        int g = keyBase + t * 8 + j;
        if (g < MM) rowptr[g] = e0 + run;
        deg[t * 8 + j] = run;
        run += loc[j];
    }
    __syncthreads();
    for (int e = e0 + t; e < e1; e += 256) {
        unsigned int v = ebuf[e];
        int lk = v >> 17;
        int pos = e0 + atomicAdd(&deg[lk], 1);
        rec[pos] = (int)(v & 0x1FFFFu);
    }
}

// ---------------- fp32 -> bf16 row conversion ----------------

__global__ void k_tobf16(const float* __restrict__ X, unsigned short* __restrict__ Xb) {
    int i = blockIdx.x * 256 + threadIdx.x;
    if (i >= NN * DD / 4) return;
    float4 v = ((const float4*)X)[i];
    ushort4 o;
    o.x = f32_to_bf16(v.x); o.y = f32_to_bf16(v.y);
    o.z = f32_to_bf16(v.z); o.w = f32_to_bf16(v.w);
    ((ushort4*)Xb)[i] = o;
}

// ---------------- aggregation: wave per dst, 8 lanes per segment ----------------
// mean layout: [N][512] bf16, k = r*64 + d. Edge loop unrolled x4 so the
// rec->Xb dependent chains of consecutive edges overlap.

__global__ void k_agg(const unsigned short* __restrict__ Xb,
                      const int* __restrict__ rowptr,
                      const int* __restrict__ rec,
                      unsigned short* __restrict__ mean) {
    int wv = threadIdx.x >> 6;
    int lane = threadIdx.x & 63;
    int n = blockIdx.x * 4 + wv;
    if (n >= NN) return;
    int r = lane >> 3;       // segment 0..7
    int q = lane & 7;        // dim-octet 0..7
    int e0 = rowptr[n * RR + r];
    int e1 = rowptr[n * RR + r + 1];
    float a0[8] = {0,0,0,0,0,0,0,0};
    float a1[8] = {0,0,0,0,0,0,0,0};
    float a2[8] = {0,0,0,0,0,0,0,0};
    float a3[8] = {0,0,0,0,0,0,0,0};
    int e = e0;
    for (; e + 3 < e1; e += 4) {
        int s0 = rec[e], s1 = rec[e + 1], s2 = rec[e + 2], s3 = rec[e + 3];
        uint4 u0 = *(const uint4*)(Xb + (size_t)s0 * DD + q * 8);
        uint4 u1 = *(const uint4*)(Xb + (size_t)s1 * DD + q * 8);
        uint4 u2 = *(const uint4*)(Xb + (size_t)s2 * DD + q * 8);
        uint4 u3 = *(const uint4*)(Xb + (size_t)s3 * DD + q * 8);
        a0[0] += bflo(u0.x); a0[1] += bfhi(u0.x); a0[2] += bflo(u0.y); a0[3] += bfhi(u0.y);
        a0[4] += bflo(u0.z); a0[5] += bfhi(u0.z); a0[6] += bflo(u0.w); a0[7] += bfhi(u0.w);
        a1[0] += bflo(u1.x); a1[1] += bfhi(u1.x); a1[2] += bflo(u1.y); a1[3] += bfhi(u1.y);
        a1[4] += bflo(u1.z); a1[5] += bfhi(u1.z); a1[6] += bflo(u1.w); a1[7] += bfhi(u1.w);
        a2[0] += bflo(u2.x); a2[1] += bfhi(u2.x); a2[2] += bflo(u2.y); a2[3] += bfhi(u2.y);
        a2[4] += bflo(u2.z); a2[5] += bfhi(u2.z); a2[6] += bflo(u2.w); a2[7] += bfhi(u2.w);
        a3[0] += bflo(u3.x); a3[1] += bfhi(u3.x); a3[2] += bflo(u3.y); a3[3] += bfhi(u3.y);
        a3[4] += bflo(u3.z); a3[5] += bfhi(u3.z); a3[6] += bflo(u3.w); a3[7] += bfhi(u3.w);
    }
    if (e + 1 < e1) {
        int s0 = rec[e], s1 = rec[e + 1];
        uint4 u0 = *(const uint4*)(Xb + (size_t)s0 * DD + q * 8);
        uint4 u1 = *(const uint4*)(Xb + (size_t)s1 * DD + q * 8);
        a0[0] += bflo(u0.x); a0[1] += bfhi(u0.x); a0[2] += bflo(u0.y); a0[3] += bfhi(u0.y);
        a0[4] += bflo(u0.z); a0[5] += bfhi(u0.z); a0[6] += bflo(u0.w); a0[7] += bfhi(u0.w);
        a1[0] += bflo(u1.x); a1[1] += bfhi(u1.x); a1[2] += bflo(u1.y); a1[3] += bfhi(u1.y);
        a1[4] += bflo(u1.z); a1[5] += bfhi(u1.z); a1[6] += bflo(u1.w); a1[7] += bfhi(u1.w);
        e += 2;
    }
    if (e < e1) {
        int s0 = rec[e];
        uint4 u0 = *(const uint4*)(Xb + (size_t)s0 * DD + q * 8);
        a0[0] += bflo(u0.x); a0[1] += bfhi(u0.x); a0[2] += bflo(u0.y); a0[3] += bfhi(u0.y);
        a0[4] += bflo(u0.z); a0[5] += bfhi(u0.z); a0[6] += bflo(u0.w); a0[7] += bfhi(u0.w);
    }
    int cnt = e1 - e0;
    float inv = 1.0f / (float)(cnt > 1 ? cnt : 1);
    uint4 o;
    o.x = (unsigned)f32_to_bf16((a0[0]+a1[0]+a2[0]+a3[0]) * inv) | ((unsigned)f32_to_bf16((a0[1]+a1[1]+a2[1]+a3[1]) * inv) << 16);
    o.y = (unsigned)f32_to_bf16((a0[2]+a1[2]+a2[2]+a3[2]) * inv) | ((unsigned)f32_to_bf16((a0[3]+a1[3]+a2[3]+a3[3]) * inv) << 16);
    o.z = (unsigned)f32_to_bf16((a0[4]+a1[4]+a2[4]+a3[4]) * inv) | ((unsigned)f32_to_bf16((a0[5]+a1[5]+a2[5]+a3[5]) * inv) << 16);
    o.w = (unsigned)f32_to_bf16((a0[6]+a1[6]+a2[6]+a3[6]) * inv) | ((unsigned)f32_to_bf16((a0[7]+a1[7]+a2[7]+a3[7]) * inv) << 16);
    *(uint4*)(mean + (size_t)n * 512 + r * 64 + q * 8) = o;
}

// ---------------- weight prep: WcT[64][576] bf16, k = r*64+d (+root tail) ----------------

__global__ void k_prepw(const float* __restrict__ W, const float* __restrict__ Root,
                        unsigned short* __restrict__ WcT) {
    int i = blockIdx.x * 256 + threadIdx.x;
    if (i >= 64 * KTOT) return;
    int o = i / KTOT;
    int k = i - o * KTOT;
    float v;
    if (k < 512) v = W[(size_t)(k >> 6) * 4096 + (k & 63) * 64 + o];
    else         v = Root[(k - 512) * 64 + o];
    WcT[(size_t)o * KTOT + k] = f32_to_bf16(v);
}

// ---------------- MFMA GEMM: out[N][64] = [mean | Xb] @ Wc + bias ----------------
// B (WcT) staged in LDS (padded stride). Wave: 32 rows x 64 cols.
// Optional fused column-stats (sum, sumsq) for BN.

__global__ __launch_bounds__(256) void k_gemm(const unsigned short* __restrict__ meanB,
                                              const unsigned short* __restrict__ Xb,
                                              const unsigned short* __restrict__ WcT,
                                              const float* __restrict__ bias,
                                              float* __restrict__ Out,
                                              float* __restrict__ stats,
                                              int dostats) {
    __shared__ unsigned short Bs[64 * BSTRIDE];   // 73 KB
    __shared__ float ssum[4][64];
    __shared__ float ssq[4][64];
    int t = threadIdx.x;
    // stage WcT -> Bs: 64 rows x 72 uint4 chunks = 4608 chunks
#pragma unroll
    for (int i = 0; i < 18; ++i) {
        int idx = i * 256 + t;
        int row = idx / 72;
        int k16 = idx - row * 72;
        uint4 v = *(const uint4*)(WcT + (size_t)row * KTOT + k16 * 8);
        *(uint4*)(Bs + row * BSTRIDE + k16 * 8) = v;
    }
    __syncthreads();

    int wv = t >> 6, lane = t & 63;
    int quad = lane >> 4, m16 = lane & 15;
    int row0 = blockIdx.x * 128 + wv * 32;
    int r0 = row0 + m16;
    int r1 = row0 + 16 + m16;
    bool ok0 = r0 < NN, ok1 = r1 < NN;

    union AU { uint4 u; bf16x8 f; };
    f32x4 acc[2][4];
#pragma unroll
    for (int i = 0; i < 2; ++i)
#pragma unroll
        for (int j = 0; j < 4; ++j) acc[i][j] = (f32x4){0.f, 0.f, 0.f, 0.f};

    const unsigned short* a0p = meanB + (size_t)r0 * 512 + quad * 8;
    const unsigned short* a1p = meanB + (size_t)r1 * 512 + quad * 8;
    const unsigned short* x0p = Xb + (size_t)r0 * DD + quad * 8;
    const unsigned short* x1p = Xb + (size_t)r1 * DD + quad * 8;
    const unsigned short* bs  = Bs + m16 * BSTRIDE + quad * 8;

#pragma unroll
    for (int kb = 0; kb < 16; ++kb) {
        AU av0, av1, bv[4];
        if (ok0) av0.u = *(const uint4*)(a0p + kb * 32); else av0.u = make_uint4(0,0,0,0);
        if (ok1) av1.u = *(const uint4*)(a1p + kb * 32); else av1.u = make_uint4(0,0,0,0);
#pragma unroll
        for (int nt = 0; nt < 4; ++nt)
            bv[nt].u = *(const uint4*)(bs + nt * 16 * BSTRIDE + kb * 32);
#pragma unroll
        for (int nt = 0; nt < 4; ++nt) {
            acc[0][nt] = __builtin_amdgcn_mfma_f32_16x16x32_bf16(av0.f, bv[nt].f, acc[0][nt], 0, 0, 0);
            acc[1][nt] = __builtin_amdgcn_mfma_f32_16x16x32_bf16(av1.f, bv[nt].f, acc[1][nt], 0, 0, 0);
        }
    }
#pragma unroll
    for (int kb = 0; kb < 2; ++kb) {
        AU av0, av1, bv[4];
        if (ok0) av0.u = *(const uint4*)(x0p + kb * 32); else av0.u = make_uint4(0,0,0,0);
        if (ok1) av1.u = *(const uint4*)(x1p + kb * 32); else av1.u = make_uint4(0,0,0,0);
#pragma unroll
        for (int nt = 0; nt < 4; ++nt)
            bv[nt].u = *(const uint4*)(bs + nt * 16 * BSTRIDE + 512 + kb * 32);
#pragma unroll
        for (int nt = 0; nt < 4; ++nt) {
            acc[0][nt] = __builtin_amdgcn_mfma_f32_16x16x32_bf16(av0.f, bv[nt].f, acc[0][nt], 0, 0, 0);
            acc[1][nt] = __builtin_amdgcn_mfma_f32_16x16x32_bf16(av1.f, bv[nt].f, acc[1][nt], 0, 0, 0);
        }
    }

#pragma unroll
    for (int rt = 0; rt < 2; ++rt) {
#pragma unroll
        for (int nt = 0; nt < 4; ++nt) {
            int col = nt * 16 + m16;
            float bb = bias[col];
#pragma unroll
            for (int i = 0; i < 4; ++i) {
                int row = row0 + rt * 16 + quad * 4 + i;
                if (row < NN) Out[(size_t)row * 64 + col] = acc[rt][nt][i] + bb;
            }
        }
    }

    if (dostats) {
#pragma unroll
        for (int nt = 0; nt < 4; ++nt) {
            int col = nt * 16 + m16;
            float bb = bias[col];
            float s = 0.f, sq = 0.f;
#pragma unroll
            for (int rt = 0; rt < 2; ++rt) {
#pragma unroll
                for (int i = 0; i < 4; ++i) {
                    int row = row0 + rt * 16 + quad * 4 + i;
                    if (row < NN) {
                        float v = acc[rt][nt][i] + bb;
                        s += v; sq += v * v;
                    }
                }
            }
            s += __shfl_xor(s, 16); s += __shfl_xor(s, 32);
            sq += __shfl_xor(sq, 16); sq += __shfl_xor(sq, 32);
            if (quad == 0) { ssum[wv][col] = s; ssq[wv][col] = sq; }
        }
        __syncthreads();
        if (t < 128) {
            int col = t & 63;
            if (t < 64) {
                float s = ssum[0][col] + ssum[1][col] + ssum[2][col] + ssum[3][col];
                atomicAdd(&stats[col], s);
            } else {
                float sq = ssq[0][col] + ssq[1][col] + ssq[2][col] + ssq[3][col];
                atomicAdd(&stats[64 + col], sq);
            }
        }
    }
}

// ---------------- BN+ReLU (in-place, + bf16 copy) ----------------

__global__ void k_bnrelu(float* __restrict__ H, unsigned short* __restrict__ Hb,
                         const float* __restrict__ stats,
                         const float* __restrict__ gamma, const float* __restrict__ beta) {
    int idx = blockIdx.x * 256 + threadIdx.x;
    const int total = NN * DD / 4;
    if (idx >= total) return;
    int c0 = (idx & 15) * 4;
    float4 v = ((const float4*)H)[idx];
    float inv = 1.0f / (float)NN;
    float4 o;
    {
        float mu = stats[c0 + 0] * inv;
        float var = stats[64 + c0 + 0] * inv - mu * mu;
        float sc = gamma[c0 + 0] * rsqrtf(var + BN_EPS);
        float r = sc * (v.x - mu) + beta[c0 + 0];
        o.x = r > 0.f ? r : 0.f;
    }
    {
        float mu = stats[c0 + 1] * inv;
        float var = stats[64 + c0 + 1] * inv - mu * mu;
        float sc = gamma[c0 + 1] * rsqrtf(var + BN_EPS);
        float r = sc * (v.y - mu) + beta[c0 + 1];
        o.y = r > 0.f ? r : 0.f;
    }
    {
        float mu = stats[c0 + 2] * inv;
        float var = stats[64 + c0 + 2] * inv - mu * mu;
        float sc = gamma[c0 + 2] * rsqrtf(var + BN_EPS);
        float r = sc * (v.z - mu) + beta[c0 + 2];
        o.z = r > 0.f ? r : 0.f;
    }
    {
        float mu = stats[c0 + 3] * inv;
        float var = stats[64 + c0 + 3] * inv - mu * mu;
        float sc = gamma[c0 + 3] * rsqrtf(var + BN_EPS);
        float r = sc * (v.w - mu) + beta[c0 + 3];
        o.w = r > 0.f ? r : 0.f;
    }
    ((float4*)H)[idx] = o;
    ushort4 ob;
    ob.x = f32_to_bf16(o.x); ob.y = f32_to_bf16(o.y);
    ob.z = f32_to_bf16(o.z); ob.w = f32_to_bf16(o.w);
    ((ushort4*)Hb)[idx] = ob;
}

// ---------------- launch ----------------

static inline size_t alignup(size_t x) { return (x + 255) & ~(size_t)255; }

extern "C" void kernel_launch(void* const* d_in, const int* in_sizes, int n_in,
                              void* d_out, int out_size, void* d_ws, size_t ws_size,
                              hipStream_t stream) {
    const float* x      = (const float*)d_in[0];
    const int*   eidx   = (const int*)d_in[1];
    const int*   etype  = (const int*)d_in[2];
    const float* w1     = (const float*)d_in[3];
    const float* root1  = (const float*)d_in[4];
    const float* b1     = (const float*)d_in[5];
    const float* gamma1 = (const float*)d_in[6];
    const float* beta1  = (const float*)d_in[7];
    const float* w2     = (const float*)d_in[8];
    const float* root2  = (const float*)d_in[9];
    const float* b2     = (const float*)d_in[10];
    float* out = (float*)d_out;

    const int* src = eidx;
    const int* dst = eidx + EE;

    char* w = (char*)d_ws;
    int* rowptr = (int*)w;            w += alignup((size_t)(MM + 1) * 4);
    int* btot   = (int*)w;            w += alignup(512 * 4);
    int* bbase  = (int*)w;            w += alignup(512 * 4);
    int* gcur   = (int*)w;            w += alignup(512 * 4);
    int* rec    = (int*)w;            w += alignup((size_t)EE * 4);
    unsigned short* mean = (unsigned short*)w; w += alignup((size_t)NN * 512 * 2);
    float* h    = (float*)w;          w += alignup((size_t)NN * DD * 4);
    unsigned short* xhb = (unsigned short*)w; w += alignup((size_t)NN * DD * 2);
    unsigned short* wct1 = (unsigned short*)w; w += alignup((size_t)64 * KTOT * 2);
    unsigned short* wct2 = (unsigned short*)w; w += alignup((size_t)64 * KTOT * 2);
    float* stats = (float*)w;         w += alignup(128 * 4);
    unsigned int* ebuf = (unsigned int*)mean;   // alias: dead before k_agg writes mean

    hipMemsetAsync(btot, 0, 512 * 4, stream);
    hipMemsetAsync(stats, 0, 128 * 4, stream);

    k_prepw<<<dim3(144), dim3(256), 0, stream>>>(w1, root1, wct1);
    k_prepw<<<dim3(144), dim3(256), 0, stream>>>(w2, root2, wct2);
    k_tobf16<<<dim3(NN * DD / 4 / 256 + 1), dim3(256), 0, stream>>>(x, xhb);

    // bucketed CSR build
    k_bcount<<<dim3(NBIN), dim3(256), 0, stream>>>(dst, btot);
    k_bscan<<<dim3(1), dim3(512), 0, stream>>>(btot, bbase, gcur, rowptr);
    k_bin<<<dim3(NBIN), dim3(256), 0, stream>>>(src, dst, etype, gcur, ebuf);
    k_bcsr<<<dim3(NB), dim3(256), 0, stream>>>(bbase, ebuf, rowptr, rec);

    // layer 1 (gemm fuses BN column stats)
    k_agg<<<dim3((NN + 3) / 4), dim3(256), 0, stream>>>(xhb, rowptr, rec, mean);
    k_gemm<<<dim3((NN + 127) / 128), dim3(256), 0, stream>>>(mean, xhb, wct1, b1, h, stats, 1);
    k_bnrelu<<<dim3(NN * DD / 4 / 256), dim3(256), 0, stream>>>(h, xhb, stats, gamma1, beta1);

    // layer 2 (xhb now holds bf16 of post-BN/ReLU h)
    k_agg<<<dim3((NN + 3) / 4), dim3(256), 0, stream>>>(xhb, rowptr, rec, mean);
    k_gemm<<<dim3((NN + 127) / 128), dim3(256), 0, stream>>>(mean, xhb, wct2, b2, out, stats, 0);
}